// Round 3
// baseline (437.869 us; speedup 1.0000x reference)
//
#include <hip/hip_runtime.h>

// GroupBatchNorm: B=512, C=65536, G=4096, fp32 in/out.
// R6: single PLAIN-LAUNCH kernel with software grid barrier.
//   R5's hipLaunchCooperativeKernel silently failed (absmax == max|ref| ->
//   output never written; coop launch is incompatible with the harness's
//   graph capture). Same fused pipeline, but:
//   - sense-reversing barrier via agent-scope atomics + __threadfence
//     (gfx94x+: emits buffer_wbl2/buffer_inv -> cross-XCD safe)
//   - co-residency GUARANTEED: 512 blocks = 2/CU exactly, launch_bounds
//     (256,2), 0 LDS -> no deadlock possible
//   - P3 fused into P4: each thread owns a fixed channel-quad (NT % Q == 0),
//     computes 4 channels' scale/shift inline from the 48 KB group accums
//     (L2-hot), streams 64 x-quads against registers. 2 barriers total.
// Phases:
//   P0 zero group accums (first G threads)
//   P1 per-(chunk,quad) partial sum/sumsq: SPLIT=8 chunks x 64 rows,
//      8 float4 register-batched loads   | barrier
//   P2 per-channel reduce over 8 chunks (coalesced) + atomic group scatter
//      (196K atomics over 12 KB)         | barrier
//   P4 streaming normalize: inline group finalize, 64 float4/thread

constexpr int B = 512;
constexpr int C = 65536;
constexpr int G = 4096;
constexpr int NBLK = 512;             // 2 blocks/CU x 256 CUs -> co-resident
constexpr int NTHR = 256;
constexpr int NT = NBLK * NTHR;       // 131072 threads
constexpr int Q = C / 4;              // 16384 channel-quads (pow2)
constexpr int SPLIT = NT / Q;         // 8 batch chunks
constexpr int ROWS = B / SPLIT;       // 64 rows per chunk
constexpr int BATCH = 8;              // float4 loads in flight per thread
#define EPS 1e-5f

// Device-global scratch (module-load allocated, zero-inited).
__device__ float g_part1[SPLIT * C];  // 2 MB per-chunk channel sums
__device__ float g_part2[SPLIT * C];  // 2 MB per-chunk channel sumsq
__device__ float g_gsum[G];
__device__ float g_gsum2[G];
__device__ float g_gcnt[G];
__device__ unsigned g_bar;            // barrier arrival counter (ends at 0)
__device__ unsigned g_sense;          // barrier generation (monotonic)

__device__ __forceinline__ void grid_barrier() {
    __syncthreads();
    if (threadIdx.x == 0) {
        __threadfence();  // release all prior writes (L2 writeback, device scope)
        unsigned gen = __hip_atomic_load(&g_sense, __ATOMIC_RELAXED,
                                         __HIP_MEMORY_SCOPE_AGENT);
        unsigned arrived = __hip_atomic_fetch_add(&g_bar, 1u, __ATOMIC_ACQ_REL,
                                                  __HIP_MEMORY_SCOPE_AGENT);
        if (arrived == NBLK - 1) {
            // last to arrive: reset counter, then flip sense (release orders
            // the reset before the flip for acquire spinners)
            __hip_atomic_store(&g_bar, 0u, __ATOMIC_RELAXED,
                               __HIP_MEMORY_SCOPE_AGENT);
            __hip_atomic_store(&g_sense, gen + 1u, __ATOMIC_RELEASE,
                               __HIP_MEMORY_SCOPE_AGENT);
        } else {
            while (__hip_atomic_load(&g_sense, __ATOMIC_ACQUIRE,
                                     __HIP_MEMORY_SCOPE_AGENT) == gen)
                __builtin_amdgcn_s_sleep(2);
        }
        __threadfence();  // acquire: invalidate stale L1/L2 before phase reads
    }
    __syncthreads();
}

__global__ __launch_bounds__(NTHR, 2) void fused_k(
    const float* __restrict__ x, const int* __restrict__ cg,
    const float* __restrict__ gamma, const float* __restrict__ beta,
    float* __restrict__ out) {
    const int n = blockIdx.x * NTHR + threadIdx.x;

    // ---- P0: zero group accumulators (disjoint from P1's writes)
    if (n < G) {
        g_gsum[n] = 0.0f;
        g_gsum2[n] = 0.0f;
        g_gcnt[n] = 0.0f;
    }

    // ---- P1: partial sums. n -> (chunk, quad); exactly NT tasks.
    {
        const int c4 = n & (Q - 1);
        const int chunk = n / Q;  // 8 chunks of 64 rows
        const float4* __restrict__ xp =
            (const float4*)(x + (size_t)chunk * ROWS * C) + c4;
        float4 s = {0.f, 0.f, 0.f, 0.f};
        float4 s2 = {0.f, 0.f, 0.f, 0.f};
        float4 vbuf[BATCH];
        for (int base = 0; base < ROWS; base += BATCH) {
#pragma unroll
            for (int j = 0; j < BATCH; ++j)
                vbuf[j] = xp[(size_t)(base + j) * Q];
#pragma unroll
            for (int j = 0; j < BATCH; ++j) {
                float4 v = vbuf[j];
                s.x += v.x; s.y += v.y; s.z += v.z; s.w += v.w;
                s2.x = fmaf(v.x, v.x, s2.x);
                s2.y = fmaf(v.y, v.y, s2.y);
                s2.z = fmaf(v.z, v.z, s2.z);
                s2.w = fmaf(v.w, v.w, s2.w);
            }
        }
        ((float4*)g_part1)[(size_t)chunk * Q + c4] = s;
        ((float4*)g_part2)[(size_t)chunk * Q + c4] = s2;
    }
    grid_barrier();

    // ---- P2: per-channel reduce over chunks (coalesced), group scatter.
    if (n < C) {
        float s = 0.f, s2 = 0.f;
#pragma unroll
        for (int k = 0; k < SPLIT; ++k) {
            s += g_part1[(size_t)k * C + n];
            s2 += g_part2[(size_t)k * C + n];
        }
        const int g = cg[n];
        atomicAdd(&g_gsum[g], s);
        atomicAdd(&g_gsum2[g], s2);
        atomicAdd(&g_gcnt[g], 1.0f);
    }
    grid_barrier();

    // ---- P4: streaming normalize with inline per-channel finalize.
    // Grid stride NT is a multiple of Q -> this thread's channel-quad is
    // FIXED across all 64 iterations: compute scale/shift once, in registers.
    {
        const int c4 = n & (Q - 1);
        const int4 gq = ((const int4*)cg)[c4];
        float4 sc, sh;
        {
            const int gi[4] = {gq.x, gq.y, gq.z, gq.w};
            float scv[4], shv[4];
#pragma unroll
            for (int j = 0; j < 4; ++j) {
                const int g = gi[j];
                float cnt = fmaxf(g_gcnt[g] * (float)B, 1.0f);
                float mean = g_gsum[g] / cnt;
                float var = g_gsum2[g] / cnt - mean * mean;
                float inv = 1.0f / sqrtf(var + EPS);
                float s = gamma[g] * inv;
                scv[j] = s;
                shv[j] = fmaf(-mean, s, beta[g]);
            }
            sc = {scv[0], scv[1], scv[2], scv[3]};
            sh = {shv[0], shv[1], shv[2], shv[3]};
        }
        const float4* __restrict__ xin = (const float4*)x;
        float4* __restrict__ op = (float4*)out;
        constexpr int ITERS = (B * (C / 4)) / NT;  // 64
        float4 vbuf[BATCH];
#pragma unroll 1
        for (int base = 0; base < ITERS; base += BATCH) {
#pragma unroll
            for (int j = 0; j < BATCH; ++j)
                vbuf[j] = xin[(size_t)(base + j) * NT + n];
#pragma unroll
            for (int j = 0; j < BATCH; ++j) {
                float4 v = vbuf[j];
                float4 o;
                o.x = fmaf(v.x, sc.x, sh.x);
                o.y = fmaf(v.y, sc.y, sh.y);
                o.z = fmaf(v.z, sc.z, sh.z);
                o.w = fmaf(v.w, sc.w, sh.w);
                op[(size_t)(base + j) * NT + n] = o;
            }
        }
    }
}

extern "C" void kernel_launch(void* const* d_in, const int* in_sizes, int n_in,
                              void* d_out, int out_size, void* d_ws, size_t ws_size,
                              hipStream_t stream) {
    const float* x = (const float*)d_in[0];
    const int* cg = (const int*)d_in[1];
    const float* gamma = (const float*)d_in[2];
    const float* beta = (const float*)d_in[3];
    float* out = (float*)d_out;
    (void)d_ws; (void)ws_size; (void)in_sizes; (void)n_in; (void)out_size;

    fused_k<<<NBLK, NTHR, 0, stream>>>(x, cg, gamma, beta, out);
}

// Round 5
// 299.570 us; speedup vs baseline: 1.4617x; 1.4617x over previous
//
#include <hip/hip_runtime.h>

// GroupBatchNorm: B=512, C=65536, G=4096, fp32 in/out.
// R7: three plain kernels, memory-parallelism-first.
//   R6 post-mortem: fused kernel = 290 us, traffic already optimal (282 MB)
//   but rate 0.97 TB/s @ VALUBusy 1.5%, VGPR=32 (compiler collapsed the
//   8-deep load batch), 512 blocks = 8 waves/CU. The wall is missing
//   load-side memory parallelism, not launch overhead (fusion gained 0).
// Fixes:
//   - colsum_k: 2048 blocks (8 blk/CU -> 32 waves/CU), free VGPRs, 8-deep
//     float4 batches. Zeroing of group accums folded in (block 0).
//   - gsum_k: k-split x2 -> 512 blocks, 32 independent 4B loads in flight
//     per thread; atomic scatter (786K atomics over 12K addrs, ~us-scale).
//   - normfin_k: 2048 blocks, fixed channel-quad per thread (stride NT
//     divides Q), group finalize gathered ONCE per thread, then 16
//     float4 iterations batched 8-deep. cscale/cshift arrays eliminated.

constexpr int B = 512;
constexpr int C = 65536;
constexpr int G = 4096;
constexpr int Q = C / 4;            // 16384 channel-quads (pow2)
constexpr int SPLIT = 32;           // batch chunks for colsum
constexpr int ROWS = B / SPLIT;     // 16 rows per chunk
constexpr int BATCH = 8;            // float4 loads in flight per thread
#define EPS 1e-5f

// Device-global scratch (module-load allocated).
__device__ float g_part1[SPLIT * C];   // 8 MB per-chunk channel sums
__device__ float g_part2[SPLIT * C];   // 8 MB per-chunk channel sumsq
__device__ float g_gsum[G];
__device__ float g_gsum2[G];
__device__ float g_gcnt[G];

// ---- K1: per-(chunk, quad) partial sums. grid = 64*32 = 2048 blocks.
// Block 0 additionally zeroes the 48 KB group accumulators (consumed only
// by K2; kernel boundary orders it).
__global__ __launch_bounds__(256) void colsum_k(const float* __restrict__ x) {
    if (blockIdx.x == 0) {
#pragma unroll
        for (int i = threadIdx.x; i < G; i += 256) {
            g_gsum[i] = 0.0f;
            g_gsum2[i] = 0.0f;
            g_gcnt[i] = 0.0f;
        }
    }
    const int nblk_c = Q / 256;                                // 64
    const int c4 = (blockIdx.x % nblk_c) * 256 + threadIdx.x;  // channel-quad
    const int chunk = blockIdx.x / nblk_c;                     // 32 chunks
    const float4* __restrict__ xp =
        (const float4*)(x + (size_t)chunk * ROWS * C) + c4;
    float4 s = {0.f, 0.f, 0.f, 0.f};
    float4 s2 = {0.f, 0.f, 0.f, 0.f};
    float4 vbuf[BATCH];
    for (int base = 0; base < ROWS; base += BATCH) {
#pragma unroll
        for (int j = 0; j < BATCH; ++j)
            vbuf[j] = xp[(size_t)(base + j) * Q];
#pragma unroll
        for (int j = 0; j < BATCH; ++j) {
            float4 v = vbuf[j];
            s.x += v.x; s.y += v.y; s.z += v.z; s.w += v.w;
            s2.x = fmaf(v.x, v.x, s2.x);
            s2.y = fmaf(v.y, v.y, s2.y);
            s2.z = fmaf(v.z, v.z, s2.z);
            s2.w = fmaf(v.w, v.w, s2.w);
        }
    }
    ((float4*)g_part1)[(size_t)chunk * Q + c4] = s;
    ((float4*)g_part2)[(size_t)chunk * Q + c4] = s2;
}

// ---- K2: per-channel reduce over chunks + atomic group scatter.
// k-split x2: thread (c, half) reduces 16 chunks -> 512 blocks, 32
// independent scalar loads in flight per thread.
__global__ __launch_bounds__(256) void gsum_k(const int* __restrict__ cg) {
    const int t = blockIdx.x * 256 + threadIdx.x;   // 131072 threads
    const int c = t & (C - 1);                      // channel
    const int half = t >> 16;                       // 0 or 1
    const int k0 = half * (SPLIT / 2);
    float s = 0.f, s2 = 0.f;
#pragma unroll
    for (int k = 0; k < SPLIT / 2; ++k) {
        s += g_part1[(size_t)(k0 + k) * C + c];
        s2 += g_part2[(size_t)(k0 + k) * C + c];
    }
    const int g = cg[c];
    atomicAdd(&g_gsum[g], s);
    atomicAdd(&g_gsum2[g], s2);
    if (half == 0) atomicAdd(&g_gcnt[g], 1.0f);
}

// ---- K3: streaming normalize with inline per-channel finalize.
// grid = 2048 blocks -> NT = 524288 threads; NT % Q == 0 so each thread's
// channel-quad is FIXED: gather group stats once, stream 16 float4s.
constexpr int NT3 = 2048 * 256;
__global__ __launch_bounds__(256) void normfin_k(
    const float* __restrict__ x, const int* __restrict__ cg,
    const float* __restrict__ gamma, const float* __restrict__ beta,
    float* __restrict__ out) {
    const int n = blockIdx.x * 256 + threadIdx.x;
    const int c4 = n & (Q - 1);
    const int4 gq = ((const int4*)cg)[c4];
    float4 sc, sh;
    {
        const int gi[4] = {gq.x, gq.y, gq.z, gq.w};
        float scv[4], shv[4];
#pragma unroll
        for (int j = 0; j < 4; ++j) {
            const int g = gi[j];
            float cnt = fmaxf(g_gcnt[g] * (float)B, 1.0f);
            float mean = g_gsum[g] / cnt;
            float var = g_gsum2[g] / cnt - mean * mean;
            float inv = 1.0f / sqrtf(var + EPS);
            float s = gamma[g] * inv;
            scv[j] = s;
            shv[j] = fmaf(-mean, s, beta[g]);
        }
        sc = {scv[0], scv[1], scv[2], scv[3]};
        sh = {shv[0], shv[1], shv[2], shv[3]};
    }
    const float4* __restrict__ xin = (const float4*)x;
    float4* __restrict__ op = (float4*)out;
    constexpr int ITERS = (B * (C / 4)) / NT3;  // 16
    float4 vbuf[BATCH];
#pragma unroll 1
    for (int base = 0; base < ITERS; base += BATCH) {
#pragma unroll
        for (int j = 0; j < BATCH; ++j)
            vbuf[j] = xin[(size_t)(base + j) * NT3 + n];
#pragma unroll
        for (int j = 0; j < BATCH; ++j) {
            float4 v = vbuf[j];
            float4 o;
            o.x = fmaf(v.x, sc.x, sh.x);
            o.y = fmaf(v.y, sc.y, sh.y);
            o.z = fmaf(v.z, sc.z, sh.z);
            o.w = fmaf(v.w, sc.w, sh.w);
            op[(size_t)(base + j) * NT3 + n] = o;
        }
    }
}

extern "C" void kernel_launch(void* const* d_in, const int* in_sizes, int n_in,
                              void* d_out, int out_size, void* d_ws, size_t ws_size,
                              hipStream_t stream) {
    const float* x = (const float*)d_in[0];
    const int* cg = (const int*)d_in[1];
    const float* gamma = (const float*)d_in[2];
    const float* beta = (const float*)d_in[3];
    float* out = (float*)d_out;
    (void)d_ws; (void)ws_size; (void)in_sizes; (void)n_in; (void)out_size;

    colsum_k<<<(Q / 256) * SPLIT, 256, 0, stream>>>(x);
    gsum_k<<<(2 * C) / 256, 256, 0, stream>>>(cg);
    normfin_k<<<NT3 / 256, 256, 0, stream>>>(x, cg, gamma, beta, out);
}

// Round 6
// 278.626 us; speedup vs baseline: 1.5715x; 1.0752x over previous
//
#include <hip/hip_runtime.h>

// GroupBatchNorm: B=512, C=65536, G=4096, fp32 in/out.
// R8: re-anchor on R4 (best measured: 274.7 us), revert R7's regression.
//   Evidence: R4=274.7, R7=299.6, R6-fused-kernel=290 (rocprof). Traffic is
//   optimal (282 MB, R6 counters); occupancy/ILP changes moved nothing.
//   R7's one structural regression: finalize moved from once-per-channel
//   (65K threads x 5 scattered reads) to once-per-thread (524K x 20) -- an
//   8x random-gather amplification on L2-cold atomically-written lines.
// R8 = R4 pipeline with two safe micro-wins:
//   - zero_k folded into colsum_k block 0 (one fewer launch)
//   - gsum_k k-split x2 (512 blocks, 2x memory parallelism on the reduce)
//   - cfinal_k / norm_k exactly as R4 (proven fastest)

constexpr int B = 512;
constexpr int C = 65536;
constexpr int G = 4096;
constexpr int Q = C / 4;            // 16384 channel-quads (pow2)
constexpr int SPLIT = 32;           // batch chunks for colsum
constexpr int ROWS = B / SPLIT;     // 16 rows per chunk
constexpr int BATCH = 8;            // float4 loads in flight per thread
#define EPS 1e-5f

// Device-global scratch (module-load allocated; normal coarse-grained device
// memory -- R6's WRITE_SIZE confirmed partials go through TCC).
__device__ float g_part1[SPLIT * C];   // 8 MB per-chunk channel sums
__device__ float g_part2[SPLIT * C];   // 8 MB per-chunk channel sumsq
__device__ float g_gsum[G];
__device__ float g_gsum2[G];
__device__ float g_gcnt[G];
__device__ float g_cscale[C];
__device__ float g_cshift[C];

// ---- K1: per-(chunk, quad) partial sums. grid = 64*32 = 2048 blocks.
// Block 0 additionally zeroes the 48 KB group accumulators (consumed only
// by K2; kernel boundary orders it).
__global__ __launch_bounds__(256) void colsum_k(const float* __restrict__ x) {
    if (blockIdx.x == 0) {
#pragma unroll
        for (int i = threadIdx.x; i < G; i += 256) {
            g_gsum[i] = 0.0f;
            g_gsum2[i] = 0.0f;
            g_gcnt[i] = 0.0f;
        }
    }
    const int nblk_c = Q / 256;                                // 64
    const int c4 = (blockIdx.x % nblk_c) * 256 + threadIdx.x;  // channel-quad
    const int chunk = blockIdx.x / nblk_c;                     // 32 chunks
    const float4* __restrict__ xp =
        (const float4*)(x + (size_t)chunk * ROWS * C) + c4;
    float4 s = {0.f, 0.f, 0.f, 0.f};
    float4 s2 = {0.f, 0.f, 0.f, 0.f};
    float4 vbuf[BATCH];
    for (int base = 0; base < ROWS; base += BATCH) {
#pragma unroll
        for (int j = 0; j < BATCH; ++j)
            vbuf[j] = xp[(size_t)(base + j) * Q];
#pragma unroll
        for (int j = 0; j < BATCH; ++j) {
            float4 v = vbuf[j];
            s.x += v.x; s.y += v.y; s.z += v.z; s.w += v.w;
            s2.x = fmaf(v.x, v.x, s2.x);
            s2.y = fmaf(v.y, v.y, s2.y);
            s2.z = fmaf(v.z, v.z, s2.z);
            s2.w = fmaf(v.w, v.w, s2.w);
        }
    }
    ((float4*)g_part1)[(size_t)chunk * Q + c4] = s;
    ((float4*)g_part2)[(size_t)chunk * Q + c4] = s2;
}

// ---- K2: per-channel reduce over chunks + atomic group scatter.
// k-split x2: thread (c, half) reduces 16 chunks -> 512 blocks, 32
// independent scalar loads in flight per thread.
__global__ __launch_bounds__(256) void gsum_k(const int* __restrict__ cg) {
    const int t = blockIdx.x * 256 + threadIdx.x;   // 131072 threads
    const int c = t & (C - 1);                      // channel
    const int half = t >> 16;                       // 0 or 1
    const int k0 = half * (SPLIT / 2);
    float s = 0.f, s2 = 0.f;
#pragma unroll
    for (int k = 0; k < SPLIT / 2; ++k) {
        s += g_part1[(size_t)(k0 + k) * C + c];
        s2 += g_part2[(size_t)(k0 + k) * C + c];
    }
    const int g = cg[c];
    atomicAdd(&g_gsum[g], s);
    atomicAdd(&g_gsum2[g], s2);
    if (half == 0) atomicAdd(&g_gcnt[g], 1.0f);
}

// ---- K3: per-channel fused scale/shift (gather ONCE per channel).
__global__ __launch_bounds__(256) void cfinal_k(const int* __restrict__ cg,
                                                const float* __restrict__ gamma,
                                                const float* __restrict__ beta) {
    const int c = blockIdx.x * 256 + threadIdx.x;
    const int g = cg[c];
    float cnt = fmaxf(g_gcnt[g] * (float)B, 1.0f);
    float mean = g_gsum[g] / cnt;
    float var = g_gsum2[g] / cnt - mean * mean;
    float inv = 1.0f / sqrtf(var + EPS);
    float sc = gamma[g] * inv;
    g_cscale[c] = sc;
    g_cshift[c] = fmaf(-mean, sc, beta[g]);
}

// ---- K4: streaming normalize, exactly one float4 per thread; scale/shift
// read coalesced from L2-hot 512 KB tables. grid = 32768 blocks.
__global__ __launch_bounds__(256) void norm_k(const float* __restrict__ x,
                                              float* __restrict__ out) {
    const size_t i = (size_t)blockIdx.x * 256 + threadIdx.x;
    const int c4 = (int)(i & (Q - 1));  // channel-quad (pow2)
    float4 xv = ((const float4*)x)[i];
    float4 s = ((const float4*)g_cscale)[c4];
    float4 t = ((const float4*)g_cshift)[c4];
    float4 o;
    o.x = fmaf(xv.x, s.x, t.x);
    o.y = fmaf(xv.y, s.y, t.y);
    o.z = fmaf(xv.z, s.z, t.z);
    o.w = fmaf(xv.w, s.w, t.w);
    ((float4*)out)[i] = o;
}

extern "C" void kernel_launch(void* const* d_in, const int* in_sizes, int n_in,
                              void* d_out, int out_size, void* d_ws, size_t ws_size,
                              hipStream_t stream) {
    const float* x = (const float*)d_in[0];
    const int* cg = (const int*)d_in[1];
    const float* gamma = (const float*)d_in[2];
    const float* beta = (const float*)d_in[3];
    float* out = (float*)d_out;
    (void)d_ws; (void)ws_size; (void)in_sizes; (void)n_in; (void)out_size;

    colsum_k<<<(Q / 256) * SPLIT, 256, 0, stream>>>(x);
    gsum_k<<<(2 * C) / 256, 256, 0, stream>>>(cg);
    cfinal_k<<<C / 256, 256, 0, stream>>>(cg, gamma, beta);
    norm_k<<<(B * C / 4) / 256, 256, 0, stream>>>(x, out);
}